// Round 8
// baseline (73.730 us; speedup 1.0000x reference)
//
#include <hip/hip_runtime.h>
#include <math.h>

#define TT 1024
#define NN 64
#define CC 128
#define SS 128
#define CH 32          // steps per chunk
#define NCHUNK 32      // chunks covering t = 1..1024

typedef float f4 __attribute__((ext_vector_type(4)));

// DPP controls (gfx9/CDNA encodings)
#define DPP_QP_XOR1   0xB1
#define DPP_QP_XOR2   0x4E
#define DPP_WAVE_SHR1 0x138
#define DPP_ROW_MIRR  0x140
#define DPP_HALF_MIRR 0x141
#define DPP_BCAST15   0x142
#define DPP_BCAST31   0x143

template <int CTRL>
__device__ __forceinline__ float dpp_max_stage(float v) {
    int p = __builtin_amdgcn_update_dpp(__float_as_int(v), __float_as_int(v),
                                        CTRL, 0xF, 0xF, false);
    return fmaxf(v, __int_as_float(p));
}
__device__ __forceinline__ float dpp_shr1(float v) {
    int p = __builtin_amdgcn_update_dpp(0, __float_as_int(v),
                                        DPP_WAVE_SHR1, 0xF, 0xF, true);
    return __int_as_float(p);
}

// inline-asm LDS read: cannot be rematerialized/sunk by the compiler
#define DSR(dst, addr, off) \
    asm volatile("ds_read_b128 %0, %1 offset:" #off : "=v"(dst) : "v"(addr))
// counted DS wait + scheduling fence (rule #18)
#define LGKM(n) do { \
    asm volatile("s_waitcnt lgkmcnt(" #n ")" ::: "memory"); \
    __builtin_amdgcn_sched_barrier(0); } while (0)
#define ISSUE(mi, oea, oeb, opq) do { \
    DSR(gea[mi], base_e, oea); DSR(geb[mi], base_e, oeb); \
    DSR(gpq[mi], base_pq, opq); } while (0)

// Fused producer/consumer CTC forward scan. One block per batch element n.
// 5 waves: wave 0 = consumer (serial recurrence in registers), waves 1-4 =
// producers (gather+exp next chunk's emissions into double-buffered LDS).
// Consumer LDS reads are volatile-asm ds_read_b128 in a depth-2 rotating
// pipeline with counted lgkmcnt -- LDS latency fully hidden, un-collapsible.
// Recurrence math identical to verified rounds 2-7 (absmax 0).
__global__ __launch_bounds__(320, 1) void ctc_scan(
    const float* __restrict__ lp,        // [T, N, C] fp32 log-softmax
    const int*   __restrict__ targets,   // [N, S]
    const int*   __restrict__ ilen,      // [N]
    const int*   __restrict__ tlen,      // [N]
    float*       __restrict__ v_out)     // [N] terminal log-alpha
{
    const int n    = blockIdx.x;
    const int tid  = threadIdx.x;
    const int wv   = tid >> 6;           // 0 = consumer, 1..4 = producers
    const int lane = tid & 63;

    __shared__ float4 s_e[2][CH / 2][64];   // 32 KiB; [b][k][lane]
    __shared__ float4 s_pb4[2][CH / 4];     // 256 B

    const int tgA = targets[n * SS + 2 * lane];
    const int tgB = targets[n * SS + 2 * lane + 1];
    const float* lpn = lp + (size_t)n * CC;      // row t at lpn + t*NN*CC

    // ---------------- prologue: producers fill chunk 0 (t = 1..32) ----------
    if (wv != 0) {
        const int w = wv - 1;            // pairs k = w, w+4, w+8, w+12
        float va[8], vc[8];
#pragma unroll
        for (int i = 0; i < 4; ++i) {
            const int k = w + 4 * i;
            const float* rowa = lpn + (size_t)(1 + 2 * k) * (NN * CC);
            const float* rowb = lpn + (size_t)(2 + 2 * k) * (NN * CC);
            va[2*i]   = rowa[tgA]; vc[2*i]   = rowa[tgB];
            va[2*i+1] = rowb[tgA]; vc[2*i+1] = rowb[tgB];
        }
        float pbv = 0.f;
        if (lane < 8) pbv = lpn[(size_t)(1 + w * 8 + lane) * (NN * CC)];
#pragma unroll
        for (int i = 0; i < 4; ++i) {
            const int k = w + 4 * i;
            s_e[0][k][lane] = make_float4(__expf(va[2*i]),   __expf(vc[2*i]),
                                          __expf(va[2*i+1]), __expf(vc[2*i+1]));
        }
        if (lane < 8) ((float*)s_pb4[0])[w * 8 + lane] = __expf(pbv);
    }

    // consumer constants + t=0 init (reference: alpha0 zeros except s=0,1;
    // zeros in log domain == 1.0 linear)
    const int tgBm = (lane > 0) ? targets[n * SS + 2 * lane - 1] : -1;
    const float k1f = (lane > 0 && tgA != tgBm) ? 1.f : 0.f;
    const float k3f = (tgB != tgA) ? 1.f : 0.f;
    const int il    = ilen[n];
    const int vs    = 2 * tlen[n] - 1;   // odd, in [127, 255]
    const int vlane = vs >> 2;

    float a0 = 1.f, a1 = 1.f, a2 = 1.f, a3 = 1.f, ls = 0.f;
    if (wv == 0) {
        a0 = (lane == 0) ? __expf(lpn[0])   : 1.f;
        a1 = (lane == 0) ? __expf(lpn[tgA]) : 1.f;
    }
    float a3p = (lane == 0) ? 0.f : 1.f;
    float mr = 1.f, inv = 1.f;

    // LDS byte addresses (flat shared addr low 32 bits == LDS offset)
    const unsigned base_e0  = (unsigned)(size_t)(void*)&s_e[0][0][lane];
    const unsigned base_pq0 = (unsigned)(size_t)(void*)&s_pb4[0][0];

    __syncthreads();

    // ---------------- main loop: 32 chunks of 32 steps ----------------------
    for (int cc = 0; cc < NCHUNK; ++cc) {
        const int b = cc & 1;
        if (wv == 0) {
            const int t0 = 1 + cc * CH;
            const bool cap = ((unsigned)(il - 1 - t0) < (unsigned)CH);
            const unsigned base_e  = base_e0  + (unsigned)(b << 14); // 16 KiB/buf
            const unsigned base_pq = base_pq0 + (unsigned)(b << 7);  // 128 B/buf

            f4 gea[3], geb[3], gpq[3];

            auto group4 = [&](const f4& ea, const f4& eb, const f4& pq, int jbase) {
#pragma unroll
                for (int c = 0; c < 4; ++c) {
                    const int j = jbase + c;
                    const float cpa = (c==0)?ea[0]:(c==1)?ea[2]:(c==2)?eb[0]:eb[2];
                    const float cpc = (c==0)?ea[1]:(c==1)?ea[3]:(c==2)?eb[1]:eb[3];
                    const float cpb = pq[c];

                    float nb3 = fmaf(k3f, a1, a3 + a2) * cpc;
                    float a3pn = dpp_shr1(nb3);
                    float nb0 = (a0 + a3p) * cpb;
                    float nb1 = fmaf(k1f, a3p, a0 + a1) * cpa;
                    float nb2 = (a2 + a1) * cpb;

                    // renorm every 8 steps: DPP butterfly one stage per step,
                    // applied at jj==7 (stale-safe, values only shrink)
                    const int jj = j & 7;
                    if      (jj == 0) mr = fmaxf(fmaxf(nb0, nb1), fmaxf(nb2, nb3));
                    else if (jj == 1) mr = dpp_max_stage<DPP_QP_XOR1>(mr);
                    else if (jj == 2) mr = dpp_max_stage<DPP_QP_XOR2>(mr);
                    else if (jj == 3) mr = dpp_max_stage<DPP_HALF_MIRR>(mr);
                    else if (jj == 4) mr = dpp_max_stage<DPP_ROW_MIRR>(mr);
                    else if (jj == 5) mr = dpp_max_stage<DPP_BCAST15>(mr);
                    else if (jj == 6) mr = dpp_max_stage<DPP_BCAST31>(mr);
                    else {
                        const float mru = __int_as_float(
                            __builtin_amdgcn_readlane(__float_as_int(mr), 63));
                        inv = 1.0f / mru;
                        ls += __logf(mru);
                        nb0 *= inv; nb1 *= inv; nb2 *= inv; nb3 *= inv;
                    }

                    if (cap) {
                        const int t = t0 + j;
                        if (t == il - 1 && lane == vlane)
                            v_out[n] = __logf((vs & 2) ? nb3 : nb1) + ls;
                    }

                    a0 = nb0; a1 = nb1; a2 = nb2; a3 = nb3;
                    if (jj == 7) a3pn *= inv;
                    a3p = a3pn;
                }
            };

            // depth-2 asm pipeline over 8 groups (buffers rotate mod 3)
            ISSUE(0, 0,     1024,  0);
            ISSUE(1, 2048,  3072,  16);
            ISSUE(2, 4096,  5120,  32);  LGKM(6); group4(gea[0], geb[0], gpq[0], 0);
            ISSUE(0, 6144,  7168,  48);  LGKM(6); group4(gea[1], geb[1], gpq[1], 4);
            ISSUE(1, 8192,  9216,  64);  LGKM(6); group4(gea[2], geb[2], gpq[2], 8);
            ISSUE(2, 10240, 11264, 80);  LGKM(6); group4(gea[0], geb[0], gpq[0], 12);
            ISSUE(0, 12288, 13312, 96);  LGKM(6); group4(gea[1], geb[1], gpq[1], 16);
            ISSUE(1, 14336, 15360, 112); LGKM(6); group4(gea[2], geb[2], gpq[2], 20);
                                         LGKM(3); group4(gea[0], geb[0], gpq[0], 24);
                                         LGKM(0); group4(gea[1], geb[1], gpq[1], 28);
            // t = 1024 (last step of last chunk) is garbage from a clamped
            // row but is never captured (il-1 <= 1023).
        } else if (cc + 1 < NCHUNK) {
            // producers fill chunk cc+1 into the other buffer
            const int w  = wv - 1;
            const int b2 = (cc + 1) & 1;
            const int t0 = 1 + (cc + 1) * CH;
            float va[8], vc[8];
#pragma unroll
            for (int i = 0; i < 4; ++i) {
                const int k = w + 4 * i;
                int ta = t0 + 2 * k;     if (ta > TT - 1) ta = TT - 1;
                int tb = t0 + 2 * k + 1; if (tb > TT - 1) tb = TT - 1;
                const float* rowa = lpn + (size_t)ta * (NN * CC);
                const float* rowb = lpn + (size_t)tb * (NN * CC);
                va[2*i]   = rowa[tgA]; vc[2*i]   = rowa[tgB];
                va[2*i+1] = rowb[tgA]; vc[2*i+1] = rowb[tgB];
            }
            float pbv = 0.f;
            if (lane < 8) {
                int tp = t0 + w * 8 + lane; if (tp > TT - 1) tp = TT - 1;
                pbv = lpn[(size_t)tp * (NN * CC)];
            }
#pragma unroll
            for (int i = 0; i < 4; ++i) {
                const int k = w + 4 * i;
                s_e[b2][k][lane] = make_float4(__expf(va[2*i]),   __expf(vc[2*i]),
                                               __expf(va[2*i+1]), __expf(vc[2*i+1]));
            }
            if (lane < 8) ((float*)s_pb4[b2])[w * 8 + lane] = __expf(pbv);
        }
        __syncthreads();
    }
}

// loss = -logsumexp(v) over the 64 batch elements; single wave
__global__ void ctc_reduce(const float* __restrict__ v, float* __restrict__ out)
{
    const int lane = threadIdx.x;
    float x = v[lane];
    float m = x;
#pragma unroll
    for (int off = 32; off > 0; off >>= 1) m = fmaxf(m, __shfl_xor(m, off));
    float e = __expf(x - m);
#pragma unroll
    for (int off = 32; off > 0; off >>= 1) e += __shfl_xor(e, off);
    if (lane == 0) out[0] = -(m + __logf(e));
}

extern "C" void kernel_launch(void* const* d_in, const int* in_sizes, int n_in,
                              void* d_out, int out_size, void* d_ws, size_t ws_size,
                              hipStream_t stream) {
    const float* lp      = (const float*)d_in[0];
    const int*   targets = (const int*)d_in[1];
    const int*   ilen    = (const int*)d_in[2];
    const int*   tlen    = (const int*)d_in[3];

    float* v   = (float*)d_ws;    // 64 floats of scratch
    float* out = (float*)d_out;

    ctc_scan<<<NN, 320, 0, stream>>>(lp, targets, ilen, tlen, v);
    ctc_reduce<<<1, 64, 0, stream>>>(v, out);
}

// Round 9
// 71.546 us; speedup vs baseline: 1.0305x; 1.0305x over previous
//
#include <hip/hip_runtime.h>
#include <math.h>

#define TT 1024
#define NN 64
#define CC 128
#define SS 128
#define CH 32          // steps per chunk
#define NCHUNK 32      // chunks covering t = 1..1024
#define NC (NN * CC)   // floats between time rows

typedef float f4 __attribute__((ext_vector_type(4)));

// DPP controls (gfx9/CDNA encodings)
#define DPP_QP_XOR1   0xB1
#define DPP_QP_XOR2   0x4E
#define DPP_WAVE_SHR1 0x138
#define DPP_ROW_MIRR  0x140
#define DPP_HALF_MIRR 0x141
#define DPP_BCAST15   0x142
#define DPP_BCAST31   0x143

template <int CTRL>
__device__ __forceinline__ float dpp_max_stage(float v) {
    int p = __builtin_amdgcn_update_dpp(__float_as_int(v), __float_as_int(v),
                                        CTRL, 0xF, 0xF, false);
    return fmaxf(v, __int_as_float(p));
}
__device__ __forceinline__ float dpp_shr1(float v) {
    int p = __builtin_amdgcn_update_dpp(0, __float_as_int(v),
                                        DPP_WAVE_SHR1, 0xF, 0xF, true);
    return __int_as_float(p);
}

// inline-asm LDS read: cannot be rematerialized/sunk by the compiler
#define DSR(dst, addr, off) \
    asm volatile("ds_read_b128 %0, %1 offset:" #off : "=v"(dst) : "v"(addr))
#define LGKM(n) do { \
    asm volatile("s_waitcnt lgkmcnt(" #n ")" ::: "memory"); \
    __builtin_amdgcn_sched_barrier(0); } while (0)
#define VMC(n) do { \
    asm volatile("s_waitcnt vmcnt(" #n ")" ::: "memory"); \
    __builtin_amdgcn_sched_barrier(0); } while (0)
#define ISSUE(mi, oea, oeb, opq) do { \
    DSR(gea[mi], base_e, oea); DSR(geb[mi], base_e, oeb); \
    DSR(gpq[mi], base_pq, opq); } while (0)
#define BARRIER() asm volatile("s_barrier" ::: "memory")

// Fused producer/consumer CTC forward scan. One block per batch element n.
// 5 waves: wave 0 = consumer (serial recurrence in registers, verified
// round-8 asm pipeline). Waves 1-4 = producers: load full lp rows COALESCED
// via global_load_lds_dwordx4 (2 rows/instr -> no uncoalesced global gather,
// which was the 4K-cy/chunk wall), then gather targets from LDS (~2
// lanes/bank, near-free), exp, pack into s_e. Cross-chunk load pipeline kept
// alive with counted vmcnt(4) + raw s_barrier (no compiler vmcnt(0) drain).
// s_rows is written and read by the SAME wave -> needs no barrier, only its
// own vmcnt. s_e visibility: producer lgkmcnt(0) before each s_barrier.
__global__ __launch_bounds__(320, 1) void ctc_scan(
    const float* __restrict__ lp,        // [T, N, C] fp32 log-softmax
    const int*   __restrict__ targets,   // [N, S]
    const int*   __restrict__ ilen,      // [N]
    const int*   __restrict__ tlen,      // [N]
    float*       __restrict__ v_out)     // [N] terminal log-alpha
{
    const int n    = blockIdx.x;
    const int tid  = threadIdx.x;
    const int wv   = tid >> 6;           // 0 = consumer, 1..4 = producers
    const int lane = tid & 63;

    __shared__ float  s_rows[2][CH][CC];    // 32 KiB: staged lp rows (chunk parity)
    __shared__ float4 s_e[2][CH / 2][64];   // 32 KiB: packed emissions
    __shared__ float4 s_pb4[2][CH / 4];     // 256 B:  blank probs

    const int tgA = targets[n * SS + 2 * lane];
    const int tgB = targets[n * SS + 2 * lane + 1];
    const float* lpn = lp + (size_t)n * CC;      // row t at lpn + t*NC

    const int w  = wv - 1;               // producer index 0..3
    const int r0 = w * 8;                // rows r0..r0+7 of each chunk

    // issue 4 coalesced global_load_lds (2 rows each) for chunk c -> s_rows[buf]
    auto issue_rows = [&](int c, int buf) {
#pragma unroll
        for (int i = 0; i < 4; ++i) {
            const int r = r0 + 2 * i;
            int t = 1 + c * CH + r + (lane >> 5);
            if (t > TT - 1) t = TT - 1;
            const float* src = lpn + (size_t)t * NC + (lane & 31) * 4;
            __builtin_amdgcn_global_load_lds(
                (const __attribute__((address_space(1))) void*)src,
                (__attribute__((address_space(3))) void*)&s_rows[buf][r][0],
                16, 0, 0);
        }
    };
    // gather+exp+pack rows r0..r0+7 of s_rows[buf] into s_e[ebuf]/s_pb4[ebuf]
    auto gather = [&](int buf, int ebuf) {
#pragma unroll
        for (int i = 0; i < 4; ++i) {
            const int rA = r0 + 2 * i, rB = rA + 1;
            const float pa0 = s_rows[buf][rA][tgA], pc0 = s_rows[buf][rA][tgB];
            const float pa1 = s_rows[buf][rB][tgA], pc1 = s_rows[buf][rB][tgB];
            s_e[ebuf][(r0 >> 1) + i][lane] =
                make_float4(__expf(pa0), __expf(pc0), __expf(pa1), __expf(pc1));
        }
        if (lane < 8) {
            const float pbv = s_rows[buf][r0 + lane][0];
            ((float*)s_pb4[ebuf])[r0 + lane] = __expf(pbv);
        }
    };

    // ---------------- prologue ----------------------------------------------
    if (wv != 0) {
        issue_rows(0, 0);
        issue_rows(1, 1);
        VMC(4);                 // chunk-0 rows complete (chunk-1 in flight)
        gather(0, 0);
    }

    // consumer constants + t=0 init (reference: alpha0 zeros except s=0,1;
    // zeros in log domain == 1.0 linear)
    const int tgBm = (lane > 0) ? targets[n * SS + 2 * lane - 1] : -1;
    const float k1f = (lane > 0 && tgA != tgBm) ? 1.f : 0.f;
    const float k3f = (tgB != tgA) ? 1.f : 0.f;
    const int il    = ilen[n];
    const int vs    = 2 * tlen[n] - 1;   // odd, in [127, 255]
    const int vlane = vs >> 2;

    float a0 = 1.f, a1 = 1.f, a2 = 1.f, a3 = 1.f, ls = 0.f;
    if (wv == 0) {
        a0 = (lane == 0) ? __expf(lpn[0])   : 1.f;
        a1 = (lane == 0) ? __expf(lpn[tgA]) : 1.f;
    }
    float a3p = (lane == 0) ? 0.f : 1.f;
    float mr = 1.f, inv = 1.f;

    // LDS byte addresses (flat shared addr low 32 bits == LDS offset)
    const unsigned base_e0  = (unsigned)(size_t)(void*)&s_e[0][0][lane];
    const unsigned base_pq0 = (unsigned)(size_t)(void*)&s_pb4[0][0];

    __syncthreads();   // prologue barrier (full drain once -- fine)

    // ---------------- main loop: 32 chunks of 32 steps ----------------------
    for (int cc = 0; cc < NCHUNK; ++cc) {
        const int b = cc & 1;
        if (wv == 0) {
            const int t0 = 1 + cc * CH;
            const bool cap = ((unsigned)(il - 1 - t0) < (unsigned)CH);
            const unsigned base_e  = base_e0  + (unsigned)(b << 14);
            const unsigned base_pq = base_pq0 + (unsigned)(b << 7);

            f4 gea[3], geb[3], gpq[3];

            auto group4 = [&](const f4& ea, const f4& eb, const f4& pq, int jbase) {
#pragma unroll
                for (int c = 0; c < 4; ++c) {
                    const int j = jbase + c;
                    const float cpa = (c==0)?ea[0]:(c==1)?ea[2]:(c==2)?eb[0]:eb[2];
                    const float cpc = (c==0)?ea[1]:(c==1)?ea[3]:(c==2)?eb[1]:eb[3];
                    const float cpb = pq[c];

                    float nb3 = fmaf(k3f, a1, a3 + a2) * cpc;
                    float a3pn = dpp_shr1(nb3);
                    float nb0 = (a0 + a3p) * cpb;
                    float nb1 = fmaf(k1f, a3p, a0 + a1) * cpa;
                    float nb2 = (a2 + a1) * cpb;

                    // renorm every 8 steps: DPP butterfly one stage per step,
                    // applied at jj==7 (stale-safe, values only shrink)
                    const int jj = j & 7;
                    if      (jj == 0) mr = fmaxf(fmaxf(nb0, nb1), fmaxf(nb2, nb3));
                    else if (jj == 1) mr = dpp_max_stage<DPP_QP_XOR1>(mr);
                    else if (jj == 2) mr = dpp_max_stage<DPP_QP_XOR2>(mr);
                    else if (jj == 3) mr = dpp_max_stage<DPP_HALF_MIRR>(mr);
                    else if (jj == 4) mr = dpp_max_stage<DPP_ROW_MIRR>(mr);
                    else if (jj == 5) mr = dpp_max_stage<DPP_BCAST15>(mr);
                    else if (jj == 6) mr = dpp_max_stage<DPP_BCAST31>(mr);
                    else {
                        const float mru = __int_as_float(
                            __builtin_amdgcn_readlane(__float_as_int(mr), 63));
                        inv = 1.0f / mru;
                        ls += __logf(mru);
                        nb0 *= inv; nb1 *= inv; nb2 *= inv; nb3 *= inv;
                    }

                    if (cap) {
                        const int t = t0 + j;
                        if (t == il - 1 && lane == vlane)
                            v_out[n] = __logf((vs & 2) ? nb3 : nb1) + ls;
                    }

                    a0 = nb0; a1 = nb1; a2 = nb2; a3 = nb3;
                    if (jj == 7) a3pn *= inv;
                    a3p = a3pn;
                }
            };

            // depth-2 asm pipeline over 8 groups (buffers rotate mod 3)
            ISSUE(0, 0,     1024,  0);
            ISSUE(1, 2048,  3072,  16);
            ISSUE(2, 4096,  5120,  32);  LGKM(6); group4(gea[0], geb[0], gpq[0], 0);
            ISSUE(0, 6144,  7168,  48);  LGKM(6); group4(gea[1], geb[1], gpq[1], 4);
            ISSUE(1, 8192,  9216,  64);  LGKM(6); group4(gea[2], geb[2], gpq[2], 8);
            ISSUE(2, 10240, 11264, 80);  LGKM(6); group4(gea[0], geb[0], gpq[0], 12);
            ISSUE(0, 12288, 13312, 96);  LGKM(6); group4(gea[1], geb[1], gpq[1], 16);
            ISSUE(1, 14336, 15360, 112); LGKM(6); group4(gea[2], geb[2], gpq[2], 20);
                                         LGKM(3); group4(gea[0], geb[0], gpq[0], 24);
                                         LGKM(0); group4(gea[1], geb[1], gpq[1], 28);
            // t = 1024 (last step of last chunk) is garbage from a clamped
            // row but is never captured (il-1 <= 1023).
        } else {
            // producers: issue chunk cc+2 (clamped), wait chunk cc+1 rows,
            // gather chunk cc+1 into s_e. s_rows is same-wave-only.
            issue_rows(cc + 2, cc & 1);
            VMC(4);
            if (cc + 1 < NCHUNK) gather((cc + 1) & 1, (cc + 1) & 1);
            asm volatile("s_waitcnt lgkmcnt(0)" ::: "memory");
        }
        BARRIER();   // raw s_barrier: no compiler vmcnt(0) drain
    }
}

// loss = -logsumexp(v) over the 64 batch elements; single wave
__global__ void ctc_reduce(const float* __restrict__ v, float* __restrict__ out)
{
    const int lane = threadIdx.x;
    float x = v[lane];
    float m = x;
#pragma unroll
    for (int off = 32; off > 0; off >>= 1) m = fmaxf(m, __shfl_xor(m, off));
    float e = __expf(x - m);
#pragma unroll
    for (int off = 32; off > 0; off >>= 1) e += __shfl_xor(e, off);
    if (lane == 0) out[0] = -(m + __logf(e));
}

extern "C" void kernel_launch(void* const* d_in, const int* in_sizes, int n_in,
                              void* d_out, int out_size, void* d_ws, size_t ws_size,
                              hipStream_t stream) {
    const float* lp      = (const float*)d_in[0];
    const int*   targets = (const int*)d_in[1];
    const int*   ilen    = (const int*)d_in[2];
    const int*   tlen    = (const int*)d_in[3];

    float* v   = (float*)d_ws;    // 64 floats of scratch
    float* out = (float*)d_out;

    ctc_scan<<<NN, 320, 0, stream>>>(lp, targets, ilen, tlen, v);
    ctc_reduce<<<1, 64, 0, stream>>>(v, out);
}